// Round 1
// baseline (2049.975 us; speedup 1.0000x reference)
//
#include <hip/hip_runtime.h>
#include <math.h>

// Problem constants (match reference)
#define NH     4      // heads
#define RD     5      // dilation rate
#define WW     49     // window
#define DMODEL 256
#define BATCH  32
#define NTOK   4900
#define DH     64     // DMODEL / NH
#define GSEG   20     // NTOK / (WW*RD)

// ---------------------------------------------------------------------------
// C[M,Nd] = A[M,K] @ B^T + bias   (B row-major [Nd,K]); M%64==0, Nd%64==0, K%16==0
// Tile: 64x64 per block, BK=16, 256 threads, each thread 4x4 outputs.
// ---------------------------------------------------------------------------
__global__ __launch_bounds__(256)
void gemm_bt_bias(const float* __restrict__ A,
                  const float* __restrict__ Bm,
                  const float* __restrict__ bias,
                  float* __restrict__ C,
                  int M, int Nd, int K) {
    __shared__ float As[16][65];
    __shared__ float Bs[16][65];

    const int tid = threadIdx.x;
    const int tx = tid & 15;        // 0..15 -> n micro
    const int ty = tid >> 4;        // 0..15 -> m micro
    const int m0 = blockIdx.y * 64;
    const int n0 = blockIdx.x * 64;

    float acc[4][4] = {};

    const int row = tid >> 2;           // 0..63
    const int kc  = (tid & 3) << 2;     // 0,4,8,12

    for (int k0 = 0; k0 < K; k0 += 16) {
        // Stage A tile (64x16) and B tile (64x16), float4 per thread each.
        float4 av = *(const float4*)(A + (size_t)(m0 + row) * K + k0 + kc);
        float4 bv = *(const float4*)(Bm + (size_t)(n0 + row) * K + k0 + kc);
        As[kc + 0][row] = av.x;
        As[kc + 1][row] = av.y;
        As[kc + 2][row] = av.z;
        As[kc + 3][row] = av.w;
        Bs[kc + 0][row] = bv.x;
        Bs[kc + 1][row] = bv.y;
        Bs[kc + 2][row] = bv.z;
        Bs[kc + 3][row] = bv.w;
        __syncthreads();

        #pragma unroll
        for (int k = 0; k < 16; k++) {
            float a[4], b[4];
            #pragma unroll
            for (int i = 0; i < 4; i++) a[i] = As[k][ty * 4 + i];
            #pragma unroll
            for (int j = 0; j < 4; j++) b[j] = Bs[k][tx * 4 + j];
            #pragma unroll
            for (int i = 0; i < 4; i++)
                #pragma unroll
                for (int j = 0; j < 4; j++)
                    acc[i][j] = fmaf(a[i], b[j], acc[i][j]);
        }
        __syncthreads();
    }

    #pragma unroll
    for (int i = 0; i < 4; i++) {
        const size_t crow = (size_t)(m0 + ty * 4 + i) * Nd + n0 + tx * 4;
        #pragma unroll
        for (int j = 0; j < 4; j++)
            C[crow + j] = acc[i][j] + bias[n0 + tx * 4 + j];
    }
}

// ---------------------------------------------------------------------------
// Dilated local attention, in-place on q buffer.
// One block per (b, g, r, h) group: W=49 tokens x dh=64.
// ---------------------------------------------------------------------------
__global__ __launch_bounds__(256)
void attn_kernel(float* __restrict__ q) {
    const int bid = blockIdx.x;
    const int h = bid % NH;
    const int r = (bid / NH) % RD;
    const int g = (bid / (NH * RD)) % GSEG;
    const int b = bid / (NH * RD * GSEG);

    __shared__ float X[WW][DH];       // 12544 B
    __shared__ float S[WW][WW + 1];   //  9800 B

    const size_t base =
        ((size_t)b * NTOK + (size_t)g * (WW * RD) + r) * DMODEL + h * DH;
    const int tid = threadIdx.x;

    // Load the 49x64 group tile.
    for (int idx = tid; idx < WW * DH; idx += 256) {
        const int i = idx >> 6, d = idx & 63;
        X[i][d] = q[base + (size_t)i * (RD * DMODEL) + d];
    }
    __syncthreads();

    // Scores: S[i][j] = scale * <X[i], X[j]>
    const float scale = 0.125f;  // 1/sqrt(64)
    for (int p = tid; p < WW * WW; p += 256) {
        const int i = p / WW, j = p % WW;
        float s = 0.f;
        #pragma unroll
        for (int d = 0; d < DH; d++) s = fmaf(X[i][d], X[j][d], s);
        S[i][j] = s * scale;
    }
    __syncthreads();

    // Row softmax (49 rows; one thread each — tiny).
    if (tid < WW) {
        const int i = tid;
        float m = -1e30f;
        for (int j = 0; j < WW; j++) m = fmaxf(m, S[i][j]);
        float sum = 0.f;
        for (int j = 0; j < WW; j++) {
            const float e = __expf(S[i][j] - m);
            S[i][j] = e;
            sum += e;
        }
        const float inv = 1.f / sum;
        for (int j = 0; j < WW; j++) S[i][j] *= inv;
    }
    __syncthreads();

    // out[i][d] = sum_j S[i][j] * X[j][d]; write back in place (block owns slice).
    for (int idx = tid; idx < WW * DH; idx += 256) {
        const int i = idx >> 6, d = idx & 63;
        float o = 0.f;
        #pragma unroll
        for (int j = 0; j < WW; j++) o = fmaf(S[i][j], X[j][d], o);
        q[base + (size_t)i * (RD * DMODEL) + d] = o;
    }
}

// ---------------------------------------------------------------------------
extern "C" void kernel_launch(void* const* d_in, const int* in_sizes, int n_in,
                              void* d_out, int out_size, void* d_ws, size_t ws_size,
                              hipStream_t stream) {
    const float* emb = (const float*)d_in[0];
    const float* Wq  = (const float*)d_in[1];
    const float* bq  = (const float*)d_in[2];
    const float* Wo  = (const float*)d_in[3];
    const float* bo  = (const float*)d_in[4];
    float* out = (float*)d_out;
    float* q   = (float*)d_ws;   // 156800*256 floats = 160.6 MB

    const int M = BATCH * NTOK;  // 156800

    dim3 block(256);
    dim3 grid_gemm(DMODEL / 64, M / 64);   // (4, 2450)

    // q = emb @ Wq^T + bq
    gemm_bt_bias<<<grid_gemm, block, 0, stream>>>(emb, Wq, bq, q, M, DMODEL, DMODEL);

    // in-place dilated attention on q
    attn_kernel<<<dim3(BATCH * GSEG * RD * NH), block, 0, stream>>>(q);

    // out = attn_out @ Wo^T + bo
    gemm_bt_bias<<<grid_gemm, block, 0, stream>>>(q, Wo, bo, out, M, DMODEL, DMODEL);
}

// Round 2
// 1829.712 us; speedup vs baseline: 1.1204x; 1.1204x over previous
//
#include <hip/hip_runtime.h>
#include <math.h>

// Problem constants (match reference)
#define NH     4      // heads
#define RD     5      // dilation rate
#define WW     49     // window
#define DMODEL 256
#define BATCH  32
#define NTOK   4900
#define DH     64     // DMODEL / NH
#define GSEG   20     // NTOK / (WW*RD)

// ---------------------------------------------------------------------------
// C[M,Nd] = A[M,K] @ B^T + bias   (B row-major [Nd,K]); M%64==0, Nd%64==0, K%16==0
// ---------------------------------------------------------------------------
__global__ __launch_bounds__(256)
void gemm_bt_bias(const float* __restrict__ A,
                  const float* __restrict__ Bm,
                  const float* __restrict__ bias,
                  float* __restrict__ C,
                  int M, int Nd, int K) {
    __shared__ float As[16][65];
    __shared__ float Bs[16][65];

    const int tid = threadIdx.x;
    const int tx = tid & 15;
    const int ty = tid >> 4;
    const int m0 = blockIdx.y * 64;
    const int n0 = blockIdx.x * 64;

    float acc[4][4] = {};

    const int row = tid >> 2;
    const int kc  = (tid & 3) << 2;

    for (int k0 = 0; k0 < K; k0 += 16) {
        float4 av = *(const float4*)(A + (size_t)(m0 + row) * K + k0 + kc);
        float4 bv = *(const float4*)(Bm + (size_t)(n0 + row) * K + k0 + kc);
        As[kc + 0][row] = av.x;
        As[kc + 1][row] = av.y;
        As[kc + 2][row] = av.z;
        As[kc + 3][row] = av.w;
        Bs[kc + 0][row] = bv.x;
        Bs[kc + 1][row] = bv.y;
        Bs[kc + 2][row] = bv.z;
        Bs[kc + 3][row] = bv.w;
        __syncthreads();

        #pragma unroll
        for (int k = 0; k < 16; k++) {
            float a[4], b[4];
            #pragma unroll
            for (int i = 0; i < 4; i++) a[i] = As[k][ty * 4 + i];
            #pragma unroll
            for (int j = 0; j < 4; j++) b[j] = Bs[k][tx * 4 + j];
            #pragma unroll
            for (int i = 0; i < 4; i++)
                #pragma unroll
                for (int j = 0; j < 4; j++)
                    acc[i][j] = fmaf(a[i], b[j], acc[i][j]);
        }
        __syncthreads();
    }

    #pragma unroll
    for (int i = 0; i < 4; i++) {
        const size_t crow = (size_t)(m0 + ty * 4 + i) * Nd + n0 + tx * 4;
        #pragma unroll
        for (int j = 0; j < 4; j++)
            C[crow + j] = acc[i][j] + bias[n0 + tx * 4 + j];
    }
}

// ---------------------------------------------------------------------------
// Dilated local attention, in-place on q buffer.
// One block (256 thr) per (b,g,r,h) group: W=49 tokens x dh=64.
// GEMM-style 4x4 register microkernels for both S = X·Xᵀ and O = P·X.
// Key trick: pre-softmax S is symmetric, so Pᵀ[j][i] = exp(S[j][i]-m_i)·inv_i
// can be built IN PLACE from row-major S — no LDS transpose of P needed.
// ---------------------------------------------------------------------------
__global__ __launch_bounds__(256)
void attn_kernel(float* __restrict__ q) {
    const int bid = blockIdx.x;
    const int h = bid % NH;
    const int r = (bid / NH) % RD;
    const int g = (bid / (NH * RD)) % GSEG;
    const int b = bid / (NH * RD * GSEG);

    __shared__ float Xr[WW][DH];     // row-major X (PV B-operand; in-row reads free)
    __shared__ float Xt[DH][68];     // X transposed, pad 68 (scores A/B operand)
    __shared__ float S[WW][68];      // scores -> P^T in place
    __shared__ float mrow[WW];
    __shared__ float irow[WW];

    const size_t base =
        ((size_t)b * NTOK + (size_t)g * (WW * RD) + r) * DMODEL + h * DH;
    const int tid = threadIdx.x;
    const int tx = tid & 15;
    const int ty = tid >> 4;

    // Zero Xt token-columns 49..63 (so padded score cols compute to 0).
    for (int p = tid; p < DH * 16; p += 256) {
        const int d = p >> 4, i = 48 + (p & 15);
        if (i > 48) Xt[d][i] = 0.f;
    }
    // Stage the 49x64 group tile into both layouts (coalesced global reads).
    for (int p = tid; p < WW * DH; p += 256) {
        const int i = p >> 6, d = p & 63;
        const float v = q[base + (size_t)i * (RD * DMODEL) + d];
        Xr[i][d] = v;
        Xt[d][i] = v;  // 8-way-conflicted write, but only ~12/thread: negligible
    }
    __syncthreads();

    // ---- Scores: S[i][j] = scale * <X_i, X_j>, 64x64 tile, rows masked ----
    {
        float acc[4][4] = {};
        for (int d = 0; d < DH; d++) {
            float a[4], bb[4];
            #pragma unroll
            for (int i = 0; i < 4; i++) a[i] = Xt[d][ty * 4 + i];
            #pragma unroll
            for (int j = 0; j < 4; j++) bb[j] = Xt[d][tx * 4 + j];
            #pragma unroll
            for (int i = 0; i < 4; i++)
                #pragma unroll
                for (int j = 0; j < 4; j++)
                    acc[i][j] = fmaf(a[i], bb[j], acc[i][j]);
        }
        const float scale = 0.125f;  // 1/sqrt(64)
        #pragma unroll
        for (int ii = 0; ii < 4; ii++) {
            const int row = ty * 4 + ii;
            if (row < WW) {
                float4 v = make_float4(acc[ii][0] * scale, acc[ii][1] * scale,
                                       acc[ii][2] * scale, acc[ii][3] * scale);
                *(float4*)&S[row][tx * 4] = v;
            }
        }
    }
    __syncthreads();

    // ---- Softmax stats: one wave per row, shuffle reduction ----
    {
        const int wv = tid >> 6, lane = tid & 63;
        for (int i = wv; i < WW; i += 4) {
            float s = (lane < WW) ? S[i][lane] : -INFINITY;
            float m = s;
            #pragma unroll
            for (int off = 32; off > 0; off >>= 1)
                m = fmaxf(m, __shfl_xor(m, off));
            float e = (lane < WW) ? __expf(s - m) : 0.f;
            float l = e;
            #pragma unroll
            for (int off = 32; off > 0; off >>= 1)
                l += __shfl_xor(l, off);
            if (lane == 0) { mrow[i] = m; irow[i] = 1.f / l; }
        }
    }
    __syncthreads();

    // ---- In-place: S[j][i] <- P^T[j][i] = exp(S[j][i]-m_i)*inv_i (S symmetric)
    for (int p = tid; p < WW * 64; p += 256) {
        const int j = p >> 6, i = p & 63;
        if (i < WW) S[j][i] = __expf(S[j][i] - mrow[i]) * irow[i];
    }
    __syncthreads();

    // ---- O = P @ X: acc2[ii][jj] = sum_k P^T[k][4ty+ii] * Xr[k][4tx+jj] ----
    {
        float acc2[4][4] = {};
        for (int k = 0; k < WW; k++) {
            float a[4], bb[4];
            #pragma unroll
            for (int i = 0; i < 4; i++) a[i] = S[k][ty * 4 + i];
            #pragma unroll
            for (int j = 0; j < 4; j++) bb[j] = Xr[k][tx * 4 + j];
            #pragma unroll
            for (int i = 0; i < 4; i++)
                #pragma unroll
                for (int j = 0; j < 4; j++)
                    acc2[i][j] = fmaf(a[i], bb[j], acc2[i][j]);
        }
        #pragma unroll
        for (int ii = 0; ii < 4; ii++) {
            const int row = ty * 4 + ii;
            if (row < WW) {
                float4 v = make_float4(acc2[ii][0], acc2[ii][1],
                                       acc2[ii][2], acc2[ii][3]);
                *(float4*)(q + base + (size_t)row * (RD * DMODEL) + tx * 4) = v;
            }
        }
    }
}

// ---------------------------------------------------------------------------
extern "C" void kernel_launch(void* const* d_in, const int* in_sizes, int n_in,
                              void* d_out, int out_size, void* d_ws, size_t ws_size,
                              hipStream_t stream) {
    const float* emb = (const float*)d_in[0];
    const float* Wq  = (const float*)d_in[1];
    const float* bq  = (const float*)d_in[2];
    const float* Wo  = (const float*)d_in[3];
    const float* bo  = (const float*)d_in[4];
    float* out = (float*)d_out;
    float* q   = (float*)d_ws;   // 156800*256 floats = 160.6 MB

    const int M = BATCH * NTOK;  // 156800

    dim3 block(256);
    dim3 grid_gemm(DMODEL / 64, M / 64);

    gemm_bt_bias<<<grid_gemm, block, 0, stream>>>(emb, Wq, bq, q, M, DMODEL, DMODEL);
    attn_kernel<<<dim3(BATCH * GSEG * RD * NH), block, 0, stream>>>(q);
    gemm_bt_bias<<<grid_gemm, block, 0, stream>>>(q, Wo, bo, out, M, DMODEL, DMODEL);
}

// Round 3
// 395.399 us; speedup vs baseline: 5.1846x; 4.6275x over previous
//
#include <hip/hip_runtime.h>
#include <hip/hip_bf16.h>
#include <math.h>

#define NH     4
#define RD     5
#define WW     49
#define DMODEL 256
#define BATCH  32
#define NTOK   4900
#define DH     64
#define GSEG   20
#define MROWS  (BATCH * NTOK)   // 156800

typedef short bf16x8 __attribute__((ext_vector_type(8)));
typedef short bf16x4 __attribute__((ext_vector_type(4)));
typedef float f32x4  __attribute__((ext_vector_type(4)));

__device__ __forceinline__ void gl_lds16(const void* g, void* l) {
    __builtin_amdgcn_global_load_lds(
        (const __attribute__((address_space(1))) void*)g,
        (__attribute__((address_space(3))) void*)l, 16, 0, 0);
}

__device__ __forceinline__ short f2bf(float f) {
    union { __hip_bfloat16 h; short s; } u;
    u.h = __float2bfloat16(f);
    return u.s;
}

// ---------------------------------------------------------------------------
// Pre-convert Wq, Wo (fp32 [256,256]) to bf16.
// ---------------------------------------------------------------------------
__global__ __launch_bounds__(256)
void wcvt(const float* __restrict__ Wq, const float* __restrict__ Wo,
          short* __restrict__ Wqb, short* __restrict__ Wob) {
    int t = blockIdx.x * 256 + threadIdx.x;       // 0..32767 float4 units
    const float* src = (t < 16384) ? Wq : Wo;
    short* dst = (t < 16384) ? Wqb : Wob;
    int i = (t & 16383) * 4;
    float4 v = *(const float4*)(src + i);
    bf16x4 o = { f2bf(v.x), f2bf(v.y), f2bf(v.z), f2bf(v.w) };
    *(bf16x4*)(dst + i) = o;
}

// ---------------------------------------------------------------------------
// GEMM1: q_bf16 = bf16(emb_f32 @ Wq^T + bq).  128x128 tile, BK=32, 4 waves.
// ---------------------------------------------------------------------------
__global__ __launch_bounds__(256)
void gemm1_mfma(const float* __restrict__ A, const short* __restrict__ Bw,
                const float* __restrict__ bias, __hip_bfloat16* __restrict__ C) {
    __shared__ __align__(16) short As[128 * 32];
    __shared__ __align__(16) short Bs[128 * 32];
    const int tid = threadIdx.x;
    const int wv = tid >> 6, ln = tid & 63;
    const int lc = ln & 15, lq = ln >> 4;
    const int m0 = blockIdx.y * 128, n0 = blockIdx.x * 128;
    const int wm = (wv & 1) * 64, wn = (wv >> 1) * 64;

    f32x4 acc[4][4] = {};

    const int arow = tid >> 3, akc = (tid & 7) * 4;   // A staging: 32 rows/pass

    for (int k0 = 0; k0 < DMODEL; k0 += 32) {
        #pragma unroll
        for (int rr = 0; rr < 4; rr++) {
            const int row = rr * 32 + arow;
            float4 v = *(const float4*)(A + (size_t)(m0 + row) * DMODEL + k0 + akc);
            bf16x4 o = { f2bf(v.x), f2bf(v.y), f2bf(v.z), f2bf(v.w) };
            *(bf16x4*)&As[row * 32 + akc] = o;
        }
        #pragma unroll
        for (int cc = 0; cc < 2; cc++) {
            const int c = wv + cc * 4;   // chunk 0..7, 1 KB each
            gl_lds16(Bw + (size_t)(n0 + c * 16 + (ln >> 2)) * DMODEL + k0 + (ln & 3) * 8,
                     &Bs[c * 512]);
        }
        __syncthreads();

        bf16x8 af[4], bf[4];
        #pragma unroll
        for (int mi = 0; mi < 4; mi++)
            af[mi] = *(const bf16x8*)&As[(wm + mi * 16 + lc) * 32 + lq * 8];
        #pragma unroll
        for (int ni = 0; ni < 4; ni++)
            bf[ni] = *(const bf16x8*)&Bs[(wn + ni * 16 + lc) * 32 + lq * 8];
        #pragma unroll
        for (int mi = 0; mi < 4; mi++)
            #pragma unroll
            for (int ni = 0; ni < 4; ni++)
                acc[mi][ni] = __builtin_amdgcn_mfma_f32_16x16x32_bf16(
                    af[mi], bf[ni], acc[mi][ni], 0, 0, 0);
        __syncthreads();
    }

    float bv[4];
    #pragma unroll
    for (int ni = 0; ni < 4; ni++) bv[ni] = bias[n0 + wn + ni * 16 + lc];
    #pragma unroll
    for (int mi = 0; mi < 4; mi++)
        #pragma unroll
        for (int rg = 0; rg < 4; rg++) {
            const int row = m0 + wm + mi * 16 + lq * 4 + rg;
            #pragma unroll
            for (int ni = 0; ni < 4; ni++)
                C[(size_t)row * DMODEL + n0 + wn + ni * 16 + lc] =
                    __float2bfloat16(acc[mi][ni][rg] + bv[ni]);
        }
}

// ---------------------------------------------------------------------------
// GEMM2: out_f32 = q_bf16 @ Wo_bf16^T + bo.  Both operands via global_load_lds.
// ---------------------------------------------------------------------------
__global__ __launch_bounds__(256)
void gemm2_mfma(const short* __restrict__ A, const short* __restrict__ Bw,
                const float* __restrict__ bias, float* __restrict__ C) {
    __shared__ __align__(16) short As[128 * 32];
    __shared__ __align__(16) short Bs[128 * 32];
    const int tid = threadIdx.x;
    const int wv = tid >> 6, ln = tid & 63;
    const int lc = ln & 15, lq = ln >> 4;
    const int m0 = blockIdx.y * 128, n0 = blockIdx.x * 128;
    const int wm = (wv & 1) * 64, wn = (wv >> 1) * 64;

    f32x4 acc[4][4] = {};

    for (int k0 = 0; k0 < DMODEL; k0 += 32) {
        #pragma unroll
        for (int cc = 0; cc < 2; cc++) {
            const int c = wv + cc * 4;
            gl_lds16(A + (size_t)(m0 + c * 16 + (ln >> 2)) * DMODEL + k0 + (ln & 3) * 8,
                     &As[c * 512]);
            gl_lds16(Bw + (size_t)(n0 + c * 16 + (ln >> 2)) * DMODEL + k0 + (ln & 3) * 8,
                     &Bs[c * 512]);
        }
        __syncthreads();

        bf16x8 af[4], bf[4];
        #pragma unroll
        for (int mi = 0; mi < 4; mi++)
            af[mi] = *(const bf16x8*)&As[(wm + mi * 16 + lc) * 32 + lq * 8];
        #pragma unroll
        for (int ni = 0; ni < 4; ni++)
            bf[ni] = *(const bf16x8*)&Bs[(wn + ni * 16 + lc) * 32 + lq * 8];
        #pragma unroll
        for (int mi = 0; mi < 4; mi++)
            #pragma unroll
            for (int ni = 0; ni < 4; ni++)
                acc[mi][ni] = __builtin_amdgcn_mfma_f32_16x16x32_bf16(
                    af[mi], bf[ni], acc[mi][ni], 0, 0, 0);
        __syncthreads();
    }

    float bv[4];
    #pragma unroll
    for (int ni = 0; ni < 4; ni++) bv[ni] = bias[n0 + wn + ni * 16 + lc];
    #pragma unroll
    for (int mi = 0; mi < 4; mi++)
        #pragma unroll
        for (int rg = 0; rg < 4; rg++) {
            const int row = m0 + wm + mi * 16 + lq * 4 + rg;
            #pragma unroll
            for (int ni = 0; ni < 4; ni++)
                C[(size_t)row * DMODEL + n0 + wn + ni * 16 + lc] =
                    acc[mi][ni][rg] + bv[ni];
        }
}

// ---------------------------------------------------------------------------
// MFMA attention, in-place on bf16 q.  One block per (b,g,r,h) group.
// S = X·Xᵀ (both operands contiguous-K from row-major X);
// softmax in C-layout regs (quad owns 4 rows, shfl_xor 1/2/4/8 across 16 lanes);
// P → LDS (bf16) → A-frags; O = P·X with B-frags from Xᵀ.
// ---------------------------------------------------------------------------
__global__ __launch_bounds__(256)
void attn_mfma(short* __restrict__ q) {
    const int bid = blockIdx.x;
    const int h = bid & 3;
    const int r = (bid >> 2) % RD;
    const int g = (bid / (NH * RD)) % GSEG;
    const int b = bid / (NH * RD * GSEG);

    __shared__ __align__(16) short X [64 * 72];   // token-major, pad 72
    __shared__ __align__(16) short XT[64 * 72];   // d-major
    __shared__ __align__(16) short SP[64 * 72];   // P (bf16)

    const int tid = threadIdx.x;
    const int wv = tid >> 6, ln = tid & 63;
    const int lc = ln & 15, lq = ln >> 4;
    const size_t base = ((size_t)(b * NTOK + g * (WW * RD) + r)) * DMODEL + h * DH;

    // Zero pads: X rows 49..63 (cols 0..63), XT cols 49..63 (all 64 d-rows).
    for (int p = tid; p < 15 * 64; p += 256)
        X[(49 + (p >> 6)) * 72 + (p & 63)] = 0;
    for (int p = tid; p < 64 * 15; p += 256)
        XT[(p / 15) * 72 + 49 + (p % 15)] = 0;

    // Stage group tile: 8 threads x 16B per token row (128 B contiguous).
    #pragma unroll
    for (int pass = 0; pass < 2; pass++) {
        const int i = pass * 32 + (tid >> 3), ch = tid & 7;
        if (i < WW) {
            bf16x8 v = *(const bf16x8*)(q + base + (size_t)i * (RD * DMODEL) + ch * 8);
            *(bf16x8*)&X[i * 72 + ch * 8] = v;
            #pragma unroll
            for (int j = 0; j < 8; j++) XT[(ch * 8 + j) * 72 + i] = v[j];
        }
    }
    __syncthreads();

    // ---- S = X·Xᵀ: wave wv computes rows 16wv..16wv+15, all 64 cols ----
    f32x4 sa[4] = {};
    {
        const bf16x8 a0 = *(const bf16x8*)&X[(16 * wv + lc) * 72 + lq * 8];
        const bf16x8 a1 = *(const bf16x8*)&X[(16 * wv + lc) * 72 + 32 + lq * 8];
        #pragma unroll
        for (int ni = 0; ni < 4; ni++) {
            const bf16x8 b0 = *(const bf16x8*)&X[(ni * 16 + lc) * 72 + lq * 8];
            const bf16x8 b1 = *(const bf16x8*)&X[(ni * 16 + lc) * 72 + 32 + lq * 8];
            sa[ni] = __builtin_amdgcn_mfma_f32_16x16x32_bf16(a0, b0, sa[ni], 0, 0, 0);
            sa[ni] = __builtin_amdgcn_mfma_f32_16x16x32_bf16(a1, b1, sa[ni], 0, 0, 0);
        }
    }

    // ---- softmax + P write (bf16) ----
    #pragma unroll
    for (int rg = 0; rg < 4; rg++) {
        float s[4];
        float m = -1e30f;
        #pragma unroll
        for (int ni = 0; ni < 4; ni++) {
            s[ni] = sa[ni][rg] * 0.125f;          // 1/sqrt(64)
            if (ni * 16 + lc < WW) m = fmaxf(m, s[ni]);
        }
        m = fmaxf(m, __shfl_xor(m, 1));
        m = fmaxf(m, __shfl_xor(m, 2));
        m = fmaxf(m, __shfl_xor(m, 4));
        m = fmaxf(m, __shfl_xor(m, 8));
        float e[4], l_ = 0.f;
        #pragma unroll
        for (int ni = 0; ni < 4; ni++) {
            e[ni] = (ni * 16 + lc < WW) ? __expf(s[ni] - m) : 0.f;
            l_ += e[ni];
        }
        l_ += __shfl_xor(l_, 1);
        l_ += __shfl_xor(l_, 2);
        l_ += __shfl_xor(l_, 4);
        l_ += __shfl_xor(l_, 8);
        const float inv = 1.f / l_;
        const int row = 16 * wv + lq * 4 + rg;
        #pragma unroll
        for (int ni = 0; ni < 4; ni++)
            SP[row * 72 + ni * 16 + lc] = f2bf(e[ni] * inv);
    }
    // Wave reads back only its own SP rows -> no barrier needed (intra-wave dep).

    // ---- O = P·X: A from SP, B from XT ----
    f32x4 oa[4] = {};
    {
        const bf16x8 a0 = *(const bf16x8*)&SP[(16 * wv + lc) * 72 + lq * 8];
        const bf16x8 a1 = *(const bf16x8*)&SP[(16 * wv + lc) * 72 + 32 + lq * 8];
        #pragma unroll
        for (int ni = 0; ni < 4; ni++) {
            const bf16x8 b0 = *(const bf16x8*)&XT[(ni * 16 + lc) * 72 + lq * 8];
            const bf16x8 b1 = *(const bf16x8*)&XT[(ni * 16 + lc) * 72 + 32 + lq * 8];
            oa[ni] = __builtin_amdgcn_mfma_f32_16x16x32_bf16(a0, b0, oa[ni], 0, 0, 0);
            oa[ni] = __builtin_amdgcn_mfma_f32_16x16x32_bf16(a1, b1, oa[ni], 0, 0, 0);
        }
    }

    // ---- write back in place (bf16) ----
    __hip_bfloat16* qb = (__hip_bfloat16*)q;
    #pragma unroll
    for (int rg = 0; rg < 4; rg++) {
        const int i = 16 * wv + lq * 4 + rg;
        if (i < WW) {
            #pragma unroll
            for (int ni = 0; ni < 4; ni++)
                qb[base + (size_t)i * (RD * DMODEL) + ni * 16 + lc] =
                    __float2bfloat16(oa[ni][rg]);
        }
    }
}

// ---------------------------------------------------------------------------
extern "C" void kernel_launch(void* const* d_in, const int* in_sizes, int n_in,
                              void* d_out, int out_size, void* d_ws, size_t ws_size,
                              hipStream_t stream) {
    const float* emb = (const float*)d_in[0];
    const float* Wq  = (const float*)d_in[1];
    const float* bq  = (const float*)d_in[2];
    const float* Wo  = (const float*)d_in[3];
    const float* bo  = (const float*)d_in[4];
    float* out = (float*)d_out;

    // Workspace layout: q bf16 (80.28 MB) | Wq bf16 (128 KB) | Wo bf16 (128 KB)
    short* q = (short*)d_ws;
    const size_t q_elems = (size_t)MROWS * DMODEL;        // 40,140,800
    short* Wqb = q + q_elems;
    short* Wob = Wqb + DMODEL * DMODEL;

    wcvt<<<dim3(128), dim3(256), 0, stream>>>(Wq, Wo, Wqb, Wob);

    dim3 gg(DMODEL / 128, MROWS / 128);   // (2, 1225)
    gemm1_mfma<<<gg, dim3(256), 0, stream>>>(emb, Wqb, bq, (__hip_bfloat16*)q);
    attn_mfma<<<dim3(BATCH * GSEG * RD * NH), dim3(256), 0, stream>>>(q);
    gemm2_mfma<<<gg, dim3(256), 0, stream>>>(q, Wob, bo, out);
}